// Round 11
// baseline (57.197 us; speedup 1.0000x reference)
//
#include <hip/hip_runtime.h>
#include <hip/hip_bf16.h>

typedef unsigned int u32;
typedef __attribute__((ext_vector_type(4))) unsigned int u32x4;
typedef __attribute__((ext_vector_type(8))) short s16x8;
typedef __attribute__((ext_vector_type(4))) float f32x4;

// bf16 RNE of a, returned as f32 bit pattern (low 16 cleared)
__device__ __forceinline__ u32 rne_hi(float a) {
    u32 u = __float_as_uint(a);
    return (u + 0x7FFFu + ((u >> 16) & 1u)) & 0xFFFF0000u;
}
// pack bf16(a0) (low16) | bf16(a1) (high16) via HW v_cvt_pk_bf16_f32
__device__ __forceinline__ u32 pk_bf16(float a0, float a1) {
    __hip_bfloat162 pk2 = __float22bfloat162_rn(make_float2(a0, a1));
    u32 r;
    __builtin_memcpy(&r, &pk2, 4);
    return r;
}

// Round-11 k1 (= round-10 design, compile fix): 2-wave blocks (1024 x 128),
// 16 groups x 32 points. Wave w owns feature-half w (64 feats): W2 frags 64
// regs, acc 8 chains. A-tile read duplication 4x -> 2x (LDS reads halved);
// barrier spans 2 waves; launch_bounds(128,2) = 256-reg budget (no spill);
// cvt_pk_bf16 staging; no setprio (compiler interleaves stage into MFMA).
__global__ __launch_bounds__(128, 2) void k1_pointfeat(
    const float* __restrict__ x, const float* __restrict__ s,
    const float* __restrict__ W1, const float* __restrict__ b1,
    const float* __restrict__ W2, float* __restrict__ ws_part)
{
    // [buf][plane][row 32][36 u32]; row stride 144B (conflict-free, measured)
    __shared__ __align__(16) u32 Hlds[2 * 2 * 32 * 36];
    const int tid  = threadIdx.x;
    const int lane = tid & 63;
    const int w    = __builtin_amdgcn_readfirstlane(tid >> 6); // 0/1
    const int rl   = lane & 15;   // 16x16 row/col lane id
    const int kg2  = lane >> 4;   // 0..3, k-group of 8

    const int p0 = blockIdx.x * 512;     // 512 consecutive points per block

    // W2 B-frags for features w*64 + n*16 + rl; k = kg2*8 + j + sl2*32
    s16x8 wbh[4][2], wbl[4][2];          // 64 regs resident
    #pragma unroll
    for (int n = 0; n < 4; ++n)
        #pragma unroll
        for (int sl2 = 0; sl2 < 2; ++sl2)
            #pragma unroll
            for (int j = 0; j < 8; ++j) {
                float f = W2[(size_t)(kg2 * 8 + j + sl2 * 32) * 128 + w * 64 + n * 16 + rl];
                u32 hb = rne_hi(f);
                float lo = f - __uint_as_float(hb);
                u32 lb = rne_hi(lo);
                wbh[n][sl2][j] = (short)(hb >> 16);
                wbl[n][sl2][j] = (short)(lb >> 16);
            }

    float rmaxn[4] = {-3.402823466e38f, -3.402823466e38f,
                      -3.402823466e38f, -3.402823466e38f};

    // stage: wave w covers rows w*16+rl (points), lane's kg2 = k-quarter;
    // 16 h-values/lane -> 2x b128 per plane via cvt_pk packing.
#define STAGE_GROUP(GG, PX, PY, PZ, PW)                                        \
    {                                                                          \
        u32* Hw = &Hlds[((GG) & 1) * 2304 + (w * 16 + rl) * 36 + kg2 * 8];     \
        _Pragma("unroll")                                                      \
        for (int h = 0; h < 2; ++h) {                                          \
            u32 hp[4], lp[4];                                                  \
            _Pragma("unroll")                                                  \
            for (int c = 0; c < 4; ++c) {                                      \
                const int k0 = kg2 * 16 + h * 8 + c * 2;                       \
                float a0 = fmaf(PX, W1[k0],                                    \
                           fmaf(PY, W1[64 + k0],                               \
                           fmaf(PZ, W1[128 + k0],                              \
                           fmaf(PW, W1[192 + k0], b1[k0]))));                  \
                float a1 = fmaf(PX, W1[k0 + 1],                                \
                           fmaf(PY, W1[65 + k0],                               \
                           fmaf(PZ, W1[129 + k0],                              \
                           fmaf(PW, W1[193 + k0], b1[k0 + 1]))));              \
                a0 = a0 > 0.f ? a0 : 0.f;                                      \
                a1 = a1 > 0.f ? a1 : 0.f;                                      \
                u32 ph = pk_bf16(a0, a1);                                      \
                float h0 = __uint_as_float(ph << 16);                          \
                float h1 = __uint_as_float(ph & 0xFFFF0000u);                  \
                u32 pl = pk_bf16(a0 - h0, a1 - h1);                            \
                hp[c] = ph;                                                    \
                lp[c] = pl;                                                    \
            }                                                                  \
            u32x4 vh = {hp[0], hp[1], hp[2], hp[3]};                           \
            u32x4 vl = {lp[0], lp[1], lp[2], lp[3]};                           \
            *(u32x4*)(Hw + h * 4)        = vh;                                 \
            *(u32x4*)(Hw + 1152 + h * 4) = vl;                                 \
        }                                                                      \
    }

    // prologue: stage group 0, prefetch coords for group 1
    {
        const int gp = p0 + w * 16 + rl;
        float px = x[(size_t)gp * 3 + 0], py = x[(size_t)gp * 3 + 1];
        float pz = x[(size_t)gp * 3 + 2], pw = s[gp];
        STAGE_GROUP(0, px, py, pz, pw)
    }
    float pxn, pyn, pzn, pwn;
    {
        const int gp = p0 + 32 + w * 16 + rl;
        pxn = x[(size_t)gp * 3 + 0]; pyn = x[(size_t)gp * 3 + 1];
        pzn = x[(size_t)gp * 3 + 2]; pwn = s[gp];
    }

    #pragma unroll 1
    for (int g = 0; g < 16; ++g) {
        __syncthreads();   // both waves staged buf[g&1]
        const u32* Hb = &Hlds[(g & 1) * 2304];
        f32x4 acc[2][4] = {};   // [m][n], 8 independent chains
        #pragma unroll
        for (int sl2 = 0; sl2 < 2; ++sl2) {
            s16x8 ah[2], al[2];
            #pragma unroll
            for (int m = 0; m < 2; ++m) {
                const u32* base = Hb + (m * 16 + rl) * 36 + sl2 * 16 + kg2 * 4;
                ah[m] = *(const s16x8*)(base);
                al[m] = *(const s16x8*)(base + 1152);
            }
            #pragma unroll
            for (int m = 0; m < 2; ++m)
                #pragma unroll
                for (int n = 0; n < 4; ++n)
                    acc[m][n] = __builtin_amdgcn_mfma_f32_16x16x32_bf16(
                        ah[m], wbh[n][sl2], acc[m][n], 0, 0, 0);
            #pragma unroll
            for (int m = 0; m < 2; ++m)
                #pragma unroll
                for (int n = 0; n < 4; ++n)
                    acc[m][n] = __builtin_amdgcn_mfma_f32_16x16x32_bf16(
                        ah[m], wbl[n][sl2], acc[m][n], 0, 0, 0);
            #pragma unroll
            for (int m = 0; m < 2; ++m)
                #pragma unroll
                for (int n = 0; n < 4; ++n)
                    acc[m][n] = __builtin_amdgcn_mfma_f32_16x16x32_bf16(
                        al[m], wbh[n][sl2], acc[m][n], 0, 0, 0);
        }
        // overlap: stage g+1 (VALU, other buffer) + issue coords g+2
        if (g < 15) {
            STAGE_GROUP(g + 1, pxn, pyn, pzn, pwn)
            if (g < 14) {
                const int gp = p0 + (g + 2) * 32 + w * 16 + rl;
                pxn = x[(size_t)gp * 3 + 0]; pyn = x[(size_t)gp * 3 + 1];
                pzn = x[(size_t)gp * 3 + 2]; pwn = s[gp];
            }
        }
        // rmax last (acc drain point)
        #pragma unroll
        for (int m = 0; m < 2; ++m)
            #pragma unroll
            for (int n = 0; n < 4; ++n)
                #pragma unroll
                for (int r = 0; r < 4; ++r)
                    rmaxn[n] = fmaxf(rmaxn[n], acc[m][n][r]);
    }
#undef STAGE_GROUP

    // lanes l, l^16, l^32, l^48 hold the same feature column
    #pragma unroll
    for (int n = 0; n < 4; ++n) {
        rmaxn[n] = fmaxf(rmaxn[n], __shfl_xor(rmaxn[n], 16, 64));
        rmaxn[n] = fmaxf(rmaxn[n], __shfl_xor(rmaxn[n], 32, 64));
    }
    if (lane < 16) {
        #pragma unroll
        for (int n = 0; n < 4; ++n)
            ws_part[blockIdx.x * 128 + w * 64 + n * 16 + lane] = rmaxn[n];
    }
}

// Hidden layer: block = (batch, 64-unit chunk); thread = (unit, i-quarter).
__global__ __launch_bounds__(256) void k2a_hidden(
    const float* __restrict__ ws_part, const float* __restrict__ b2,
    const float* __restrict__ e,
    const float* __restrict__ W3, const float* __restrict__ b3,
    float* __restrict__ ws_hid)
{
    const int blk = blockIdx.x;        // 256 = 64 batches x 4 chunks
    const int b   = blk >> 2;
    const int c   = blk & 3;
    const int tid = threadIdx.x;
    const int u   = tid & 63;
    const int part = tid >> 6;         // 0..3, i-range quarter
    __shared__ float comb[640];
    __shared__ float psum[4][64];

    for (int i = tid; i < 640; i += 256) {
        float v;
        if (i < 128) {
            const float* __restrict__ pp = ws_part + (size_t)b * 16 * 128 + i;
            float m = pp[0];
            #pragma unroll
            for (int t = 1; t < 16; ++t) m = fmaxf(m, pp[t * 128]);
            v = m + b2[i];
        } else {
            v = e[b * 512 + (i - 128)];
        }
        comb[i] = v;
    }
    __syncthreads();

    const int gu = c * 64 + u;
    const float* __restrict__ Wp = W3 + (size_t)(part * 160) * 256 + gu;
    const float* __restrict__ cp = comb + part * 160;
    float a = 0.f;
    for (int i = 0; i < 160; ++i) a = fmaf(cp[i], Wp[(size_t)i * 256], a);
    psum[part][u] = a;
    __syncthreads();
    if (tid < 64) {
        float hv = psum[0][u] + psum[1][u] + psum[2][u] + psum[3][u] + b3[gu];
        ws_hid[b * 256 + gu] = hv > 0.f ? hv : 0.f;
    }
}

// z_e + VQ + per-batch loss partial. 64 blocks x 512 threads.
__global__ __launch_bounds__(512) void k2b_vq(
    const float* __restrict__ ws_hid,
    const float* __restrict__ W4, const float* __restrict__ b4,
    const float* __restrict__ cb, float* __restrict__ out,
    float* __restrict__ ws_loss)
{
    const int b = blockIdx.x, tid = threadIdx.x;
    __shared__ float hid[256];
    __shared__ float psum[4][128];
    __shared__ float ze[128];
    __shared__ float red_d[512];
    __shared__ int   red_i[512];
    __shared__ float lred[128];
    __shared__ float zzs;

    if (tid < 256) hid[tid] = ws_hid[b * 256 + tid];
    __syncthreads();

    {
        const int u = tid & 127, part = tid >> 7;
        const float* __restrict__ Wp = W4 + (size_t)(part * 64) * 128 + u;
        const float* __restrict__ hp = hid + part * 64;
        float a = 0.f;
        for (int i = 0; i < 64; ++i) a = fmaf(hp[i], Wp[(size_t)i * 128], a);
        psum[part][u] = a;
    }
    __syncthreads();
    if (tid < 128) {
        float a = psum[0][tid] + psum[1][tid] + psum[2][tid] + psum[3][tid] + b4[tid];
        ze[tid] = a;
        out[8192 + b * 128 + tid] = a;     // z_e
    }
    __syncthreads();

    if (tid < 64) {
        float t = ze[tid] * ze[tid] + ze[tid + 64] * ze[tid + 64];
        #pragma unroll
        for (int d = 1; d < 64; d <<= 1) t += __shfl_xor(t, d, 64);
        if (tid == 0) zzs = t;
    }
    __syncthreads();

    {
        float dot = 0.f, cc = 0.f;
        const f32x4* __restrict__ cp = (const f32x4*)(cb + (size_t)tid * 128);
        for (int k4 = 0; k4 < 32; ++k4) {
            f32x4 v = cp[k4];
            dot = fmaf(ze[k4 * 4 + 0], v.x, dot);
            cc  = fmaf(v.x, v.x, cc);
            dot = fmaf(ze[k4 * 4 + 1], v.y, dot);
            cc  = fmaf(v.y, v.y, cc);
            dot = fmaf(ze[k4 * 4 + 2], v.z, dot);
            cc  = fmaf(v.z, v.z, cc);
            dot = fmaf(ze[k4 * 4 + 3], v.w, dot);
            cc  = fmaf(v.w, v.w, cc);
        }
        red_d[tid] = zzs - 2.f * dot + cc;
        red_i[tid] = tid;
    }
    __syncthreads();

    for (int sft = 256; sft >= 1; sft >>= 1) {
        if (tid < sft) {
            float da = red_d[tid], db = red_d[tid + sft];
            int   ia = red_i[tid], ib = red_i[tid + sft];
            if (db < da || (db == da && ib < ia)) { red_d[tid] = db; red_i[tid] = ib; }
        }
        __syncthreads();
    }
    const int bc = red_i[0];

    if (tid < 128) {
        float zq  = cb[(size_t)bc * 128 + tid];
        float zev = ze[tid];
        out[b * 128 + tid] = zev + (zq - zev);   // z_q_st
        float d = zq - zev;
        lred[tid] = d * d;
    }
    if (tid == 0) out[16386 + b] = (float)bc;
    __syncthreads();
    if (tid < 64) {
        float t = lred[tid] + lred[tid + 64];
        #pragma unroll
        for (int d = 1; d < 64; d <<= 1) t += __shfl_xor(t, d, 64);
        if (tid == 0) ws_loss[b] = t;
    }
}

// Single-wave loss finalize.
__global__ void k3_loss(const float* __restrict__ ws_loss, float* __restrict__ out)
{
    const int t = threadIdx.x;   // 64 threads
    float v = ws_loss[t];
    #pragma unroll
    for (int d = 1; d < 64; d <<= 1) v += __shfl_xor(v, d, 64);
    if (t == 0) {
        float m = v / 8192.f;
        out[16384] = m;   // codebook_loss
        out[16385] = m;   // commitment_loss (numerically identical)
    }
}

extern "C" void kernel_launch(void* const* d_in, const int* in_sizes, int n_in,
                              void* d_out, int out_size, void* d_ws, size_t ws_size,
                              hipStream_t stream) {
    const float* x  = (const float*)d_in[0];
    const float* s  = (const float*)d_in[1];
    const float* e  = (const float*)d_in[2];
    const float* W1 = (const float*)d_in[3];
    const float* b1 = (const float*)d_in[4];
    const float* W2 = (const float*)d_in[5];
    const float* b2 = (const float*)d_in[6];
    const float* W3 = (const float*)d_in[7];
    const float* b3 = (const float*)d_in[8];
    const float* W4 = (const float*)d_in[9];
    const float* b4 = (const float*)d_in[10];
    const float* cb = (const float*)d_in[11];
    float* out = (float*)d_out;

    float* ws_part = (float*)d_ws;                      // 1024*128 f32 = 512 KB
    float* ws_hid  = (float*)d_ws + 1024 * 128;         // 64*256 f32 = 64 KB
    float* ws_loss = (float*)d_ws + 1024 * 128 + 64 * 256;  // 64 f32

    k1_pointfeat<<<1024, 128, 0, stream>>>(x, s, W1, b1, W2, ws_part);
    k2a_hidden<<<256, 256, 0, stream>>>(ws_part, b2, e, W3, b3, ws_hid);
    k2b_vq<<<64, 512, 0, stream>>>(ws_hid, W4, b4, cb, out, ws_loss);
    k3_loss<<<1, 64, 0, stream>>>(ws_loss, out);
}

// Round 12
// 49.357 us; speedup vs baseline: 1.1588x; 1.1588x over previous
//
#include <hip/hip_runtime.h>
#include <hip/hip_bf16.h>

typedef unsigned int u32;
typedef __attribute__((ext_vector_type(4))) unsigned int u32x4;
typedef __attribute__((ext_vector_type(8))) short s16x8;
typedef __attribute__((ext_vector_type(4))) float f32x4;

// bf16 RNE of a, returned as f32 bit pattern (low 16 cleared)
__device__ __forceinline__ u32 rne_hi(float a) {
    u32 u = __float_as_uint(a);
    return (u + 0x7FFFu + ((u >> 16) & 1u)) & 0xFFFF0000u;
}
// pack bf16(a0) (low16) | bf16(a1) (high16) via HW v_cvt_pk_bf16_f32
__device__ __forceinline__ u32 pk_bf16(float a0, float a1) {
    __hip_bfloat162 pk2 = __float22bfloat162_rn(make_float2(a0, a1));
    u32 r;
    __builtin_memcpy(&r, &pk2, 4);
    return r;
}

// Round-12 k1: round-9 partition (4 waves, point=lane, 0 bank conflicts,
// 4096 waves) + split-stage pipeline:
//   barrier -> issue sl2=0 ds_reads -> STAGE-COMPUTE(g+1) in regs (hides ds
//   latency) -> MFMA sl2=0 -> issue sl2=1 reads + coords(g+2) -> MFMA sl2=1
//   -> STAGE-WRITE(g+1, other buffer) -> rmax(g).
// No setprio: during one wave's MFMA phase, co-resident waves' stage VALU
// must be allowed to issue (setprio made the pipes serialize across waves).
__global__ __launch_bounds__(256) void k1_pointfeat(
    const float* __restrict__ x, const float* __restrict__ s,
    const float* __restrict__ W1, const float* __restrict__ b1,
    const float* __restrict__ W2, float* __restrict__ ws_part)
{
    __shared__ __align__(16) u32 Hlds[2 * 2 * 64 * 36];
    const int tid   = threadIdx.x;
    const int lane  = tid & 63;
    const int point = tid & 63;
    const int kq    = __builtin_amdgcn_readfirstlane(tid >> 6); // wave = 32-feat tile
    const int rl    = lane & 15;
    const int kg2   = lane >> 4;

    const int p0 = blockIdx.x * 512;

    // W2 B-frags for feats kq*32 + n*16 + rl; k = kg2*8 + j + sl2*32 (32 regs)
    s16x8 wbh[2][2], wbl[2][2];
    #pragma unroll
    for (int n = 0; n < 2; ++n)
        #pragma unroll
        for (int sl2 = 0; sl2 < 2; ++sl2)
            #pragma unroll
            for (int j = 0; j < 8; ++j) {
                float f = W2[(size_t)(kg2 * 8 + j + sl2 * 32) * 128 + kq * 32 + n * 16 + rl];
                u32 hb = rne_hi(f);
                float lo = f - __uint_as_float(hb);
                u32 lb = rne_hi(lo);
                wbh[n][sl2][j] = (short)(hb >> 16);
                wbl[n][sl2][j] = (short)(lb >> 16);
            }

    float rmax0 = -3.402823466e38f, rmax1 = -3.402823466e38f;

    // compute layer1 (16 h values: this wave's kq k-quarter) + split + pack
#define STAGE_COMPUTE(PX, PY, PZ, PW, VH0, VH1, VL0, VL1)                      \
    {                                                                          \
        _Pragma("unroll")                                                      \
        for (int h = 0; h < 2; ++h) {                                          \
            u32 hp[4], lp[4];                                                  \
            _Pragma("unroll")                                                  \
            for (int c = 0; c < 4; ++c) {                                      \
                const int k0 = kq * 16 + h * 8 + c * 2;                        \
                float a0 = fmaf(PX, W1[k0],                                    \
                           fmaf(PY, W1[64 + k0],                               \
                           fmaf(PZ, W1[128 + k0],                              \
                           fmaf(PW, W1[192 + k0], b1[k0]))));                  \
                float a1 = fmaf(PX, W1[k0 + 1],                                \
                           fmaf(PY, W1[65 + k0],                               \
                           fmaf(PZ, W1[129 + k0],                              \
                           fmaf(PW, W1[193 + k0], b1[k0 + 1]))));              \
                a0 = a0 > 0.f ? a0 : 0.f;                                      \
                a1 = a1 > 0.f ? a1 : 0.f;                                      \
                u32 ph = pk_bf16(a0, a1);                                      \
                float h0 = __uint_as_float(ph << 16);                          \
                float h1 = __uint_as_float(ph & 0xFFFF0000u);                  \
                u32 pl = pk_bf16(a0 - h0, a1 - h1);                            \
                hp[c] = ph; lp[c] = pl;                                        \
            }                                                                  \
            if (h == 0) { VH0 = (u32x4){hp[0],hp[1],hp[2],hp[3]};              \
                          VL0 = (u32x4){lp[0],lp[1],lp[2],lp[3]}; }            \
            else        { VH1 = (u32x4){hp[0],hp[1],hp[2],hp[3]};              \
                          VL1 = (u32x4){lp[0],lp[1],lp[2],lp[3]}; }            \
        }                                                                      \
    }
#define STAGE_WRITE(GG, VH0, VH1, VL0, VL1)                                    \
    {                                                                          \
        u32* Hw = &Hlds[((GG) & 1) * 4608 + point * 36 + kq * 8];              \
        *(u32x4*)(Hw)            = VH0;                                        \
        *(u32x4*)(Hw + 4)        = VH1;                                        \
        *(u32x4*)(Hw + 2304)     = VL0;                                        \
        *(u32x4*)(Hw + 2304 + 4) = VL1;                                        \
    }

    // prologue: stage group 0 fully; prefetch coords for group 1
    {
        const int gp = p0 + point;
        float px = x[(size_t)gp * 3 + 0], py = x[(size_t)gp * 3 + 1];
        float pz = x[(size_t)gp * 3 + 2], pw = s[gp];
        u32x4 vh0, vh1, vl0, vl1;
        STAGE_COMPUTE(px, py, pz, pw, vh0, vh1, vl0, vl1)
        STAGE_WRITE(0, vh0, vh1, vl0, vl1)
    }
    float pxn, pyn, pzn, pwn;
    {
        const int gp = p0 + 64 + point;
        pxn = x[(size_t)gp * 3 + 0]; pyn = x[(size_t)gp * 3 + 1];
        pzn = x[(size_t)gp * 3 + 2]; pwn = s[gp];
    }

    #pragma unroll 1
    for (int g = 0; g < 8; ++g) {
        __syncthreads();   // buf[g&1] staged by all waves
        const u32* Hb = &Hlds[(g & 1) * 4608];

        // issue sl2=0 A-frag reads (8 x b128)
        s16x8 ah0[4], al0[4];
        #pragma unroll
        for (int m = 0; m < 4; ++m) {
            const u32* base = Hb + (m * 16 + rl) * 36 + kg2 * 4;
            ah0[m] = *(const s16x8*)(base);
            al0[m] = *(const s16x8*)(base + 2304);
        }

        // stage-compute g+1 (VALU, independent of the ds_reads -> hides them)
        u32x4 vh0, vh1, vl0, vl1;
        if (g < 7) {
            STAGE_COMPUTE(pxn, pyn, pzn, pwn, vh0, vh1, vl0, vl1)
        }

        f32x4 acc[4][2] = {};   // [m][n], 8 independent chains
        // MFMA k-slab 0
        #pragma unroll
        for (int m = 0; m < 4; ++m)
            #pragma unroll
            for (int n = 0; n < 2; ++n)
                acc[m][n] = __builtin_amdgcn_mfma_f32_16x16x32_bf16(
                    ah0[m], wbh[n][0], acc[m][n], 0, 0, 0);
        #pragma unroll
        for (int m = 0; m < 4; ++m)
            #pragma unroll
            for (int n = 0; n < 2; ++n)
                acc[m][n] = __builtin_amdgcn_mfma_f32_16x16x32_bf16(
                    ah0[m], wbl[n][0], acc[m][n], 0, 0, 0);
        #pragma unroll
        for (int m = 0; m < 4; ++m)
            #pragma unroll
            for (int n = 0; n < 2; ++n)
                acc[m][n] = __builtin_amdgcn_mfma_f32_16x16x32_bf16(
                    al0[m], wbh[n][0], acc[m][n], 0, 0, 0);

        // issue sl2=1 A-frag reads + coords for g+2
        s16x8 ah1[4], al1[4];
        #pragma unroll
        for (int m = 0; m < 4; ++m) {
            const u32* base = Hb + (m * 16 + rl) * 36 + 16 + kg2 * 4;
            ah1[m] = *(const s16x8*)(base);
            al1[m] = *(const s16x8*)(base + 2304);
        }
        if (g < 6) {
            const int gp = p0 + (g + 2) * 64 + point;
            pxn = x[(size_t)gp * 3 + 0]; pyn = x[(size_t)gp * 3 + 1];
            pzn = x[(size_t)gp * 3 + 2]; pwn = s[gp];
        }

        // MFMA k-slab 1
        #pragma unroll
        for (int m = 0; m < 4; ++m)
            #pragma unroll
            for (int n = 0; n < 2; ++n)
                acc[m][n] = __builtin_amdgcn_mfma_f32_16x16x32_bf16(
                    ah1[m], wbh[n][1], acc[m][n], 0, 0, 0);
        #pragma unroll
        for (int m = 0; m < 4; ++m)
            #pragma unroll
            for (int n = 0; n < 2; ++n)
                acc[m][n] = __builtin_amdgcn_mfma_f32_16x16x32_bf16(
                    ah1[m], wbl[n][1], acc[m][n], 0, 0, 0);
        #pragma unroll
        for (int m = 0; m < 4; ++m)
            #pragma unroll
            for (int n = 0; n < 2; ++n)
                acc[m][n] = __builtin_amdgcn_mfma_f32_16x16x32_bf16(
                    al1[m], wbh[n][1], acc[m][n], 0, 0, 0);

        // stage-write g+1 (other buffer: no wave reads it until next barrier)
        if (g < 7) {
            STAGE_WRITE(g + 1, vh0, vh1, vl0, vl1)
        }

        // rmax last (acc drain)
        #pragma unroll
        for (int m = 0; m < 4; ++m)
            #pragma unroll
            for (int r = 0; r < 4; ++r) {
                rmax0 = fmaxf(rmax0, acc[m][0][r]);
                rmax1 = fmaxf(rmax1, acc[m][1][r]);
            }
    }
#undef STAGE_COMPUTE
#undef STAGE_WRITE

    // lanes l, l^16, l^32, l^48 hold the same feature column
    rmax0 = fmaxf(rmax0, __shfl_xor(rmax0, 16, 64));
    rmax0 = fmaxf(rmax0, __shfl_xor(rmax0, 32, 64));
    rmax1 = fmaxf(rmax1, __shfl_xor(rmax1, 16, 64));
    rmax1 = fmaxf(rmax1, __shfl_xor(rmax1, 32, 64));
    if (lane < 16) {
        ws_part[blockIdx.x * 128 + kq * 32 + lane]      = rmax0;
        ws_part[blockIdx.x * 128 + kq * 32 + 16 + lane] = rmax1;
    }
}

// Hidden layer: block = (batch, 64-unit chunk); thread = (unit, i-quarter).
__global__ __launch_bounds__(256) void k2a_hidden(
    const float* __restrict__ ws_part, const float* __restrict__ b2,
    const float* __restrict__ e,
    const float* __restrict__ W3, const float* __restrict__ b3,
    float* __restrict__ ws_hid)
{
    const int blk = blockIdx.x;        // 256 = 64 batches x 4 chunks
    const int b   = blk >> 2;
    const int c   = blk & 3;
    const int tid = threadIdx.x;
    const int u   = tid & 63;
    const int part = tid >> 6;         // 0..3, i-range quarter
    __shared__ float comb[640];
    __shared__ float psum[4][64];

    for (int i = tid; i < 640; i += 256) {
        float v;
        if (i < 128) {
            const float* __restrict__ pp = ws_part + (size_t)b * 16 * 128 + i;
            float m = pp[0];
            #pragma unroll
            for (int t = 1; t < 16; ++t) m = fmaxf(m, pp[t * 128]);
            v = m + b2[i];
        } else {
            v = e[b * 512 + (i - 128)];
        }
        comb[i] = v;
    }
    __syncthreads();

    const int gu = c * 64 + u;
    const float* __restrict__ Wp = W3 + (size_t)(part * 160) * 256 + gu;
    const float* __restrict__ cp = comb + part * 160;
    float a = 0.f;
    for (int i = 0; i < 160; ++i) a = fmaf(cp[i], Wp[(size_t)i * 256], a);
    psum[part][u] = a;
    __syncthreads();
    if (tid < 64) {
        float hv = psum[0][u] + psum[1][u] + psum[2][u] + psum[3][u] + b3[gu];
        ws_hid[b * 256 + gu] = hv > 0.f ? hv : 0.f;
    }
}

// z_e + VQ + per-batch loss partial. 64 blocks x 512 threads.
__global__ __launch_bounds__(512) void k2b_vq(
    const float* __restrict__ ws_hid,
    const float* __restrict__ W4, const float* __restrict__ b4,
    const float* __restrict__ cb, float* __restrict__ out,
    float* __restrict__ ws_loss)
{
    const int b = blockIdx.x, tid = threadIdx.x;
    __shared__ float hid[256];
    __shared__ float psum[4][128];
    __shared__ float ze[128];
    __shared__ float red_d[512];
    __shared__ int   red_i[512];
    __shared__ float lred[128];
    __shared__ float zzs;

    if (tid < 256) hid[tid] = ws_hid[b * 256 + tid];
    __syncthreads();

    {
        const int u = tid & 127, part = tid >> 7;
        const float* __restrict__ Wp = W4 + (size_t)(part * 64) * 128 + u;
        const float* __restrict__ hp = hid + part * 64;
        float a = 0.f;
        for (int i = 0; i < 64; ++i) a = fmaf(hp[i], Wp[(size_t)i * 128], a);
        psum[part][u] = a;
    }
    __syncthreads();
    if (tid < 128) {
        float a = psum[0][tid] + psum[1][tid] + psum[2][tid] + psum[3][tid] + b4[tid];
        ze[tid] = a;
        out[8192 + b * 128 + tid] = a;     // z_e
    }
    __syncthreads();

    if (tid < 64) {
        float t = ze[tid] * ze[tid] + ze[tid + 64] * ze[tid + 64];
        #pragma unroll
        for (int d = 1; d < 64; d <<= 1) t += __shfl_xor(t, d, 64);
        if (tid == 0) zzs = t;
    }
    __syncthreads();

    {
        float dot = 0.f, cc = 0.f;
        const f32x4* __restrict__ cp = (const f32x4*)(cb + (size_t)tid * 128);
        for (int k4 = 0; k4 < 32; ++k4) {
            f32x4 v = cp[k4];
            dot = fmaf(ze[k4 * 4 + 0], v.x, dot);
            cc  = fmaf(v.x, v.x, cc);
            dot = fmaf(ze[k4 * 4 + 1], v.y, dot);
            cc  = fmaf(v.y, v.y, cc);
            dot = fmaf(ze[k4 * 4 + 2], v.z, dot);
            cc  = fmaf(v.z, v.z, cc);
            dot = fmaf(ze[k4 * 4 + 3], v.w, dot);
            cc  = fmaf(v.w, v.w, cc);
        }
        red_d[tid] = zzs - 2.f * dot + cc;
        red_i[tid] = tid;
    }
    __syncthreads();

    for (int sft = 256; sft >= 1; sft >>= 1) {
        if (tid < sft) {
            float da = red_d[tid], db = red_d[tid + sft];
            int   ia = red_i[tid], ib = red_i[tid + sft];
            if (db < da || (db == da && ib < ia)) { red_d[tid] = db; red_i[tid] = ib; }
        }
        __syncthreads();
    }
    const int bc = red_i[0];

    if (tid < 128) {
        float zq  = cb[(size_t)bc * 128 + tid];
        float zev = ze[tid];
        out[b * 128 + tid] = zev + (zq - zev);   // z_q_st
        float d = zq - zev;
        lred[tid] = d * d;
    }
    if (tid == 0) out[16386 + b] = (float)bc;
    __syncthreads();
    if (tid < 64) {
        float t = lred[tid] + lred[tid + 64];
        #pragma unroll
        for (int d = 1; d < 64; d <<= 1) t += __shfl_xor(t, d, 64);
        if (tid == 0) ws_loss[b] = t;
    }
}

// Single-wave loss finalize.
__global__ void k3_loss(const float* __restrict__ ws_loss, float* __restrict__ out)
{
    const int t = threadIdx.x;   // 64 threads
    float v = ws_loss[t];
    #pragma unroll
    for (int d = 1; d < 64; d <<= 1) v += __shfl_xor(v, d, 64);
    if (t == 0) {
        float m = v / 8192.f;
        out[16384] = m;   // codebook_loss
        out[16385] = m;   // commitment_loss (numerically identical)
    }
}

extern "C" void kernel_launch(void* const* d_in, const int* in_sizes, int n_in,
                              void* d_out, int out_size, void* d_ws, size_t ws_size,
                              hipStream_t stream) {
    const float* x  = (const float*)d_in[0];
    const float* s  = (const float*)d_in[1];
    const float* e  = (const float*)d_in[2];
    const float* W1 = (const float*)d_in[3];
    const float* b1 = (const float*)d_in[4];
    const float* W2 = (const float*)d_in[5];
    const float* b2 = (const float*)d_in[6];
    const float* W3 = (const float*)d_in[7];
    const float* b3 = (const float*)d_in[8];
    const float* W4 = (const float*)d_in[9];
    const float* b4 = (const float*)d_in[10];
    const float* cb = (const float*)d_in[11];
    float* out = (float*)d_out;

    float* ws_part = (float*)d_ws;                      // 1024*128 f32 = 512 KB
    float* ws_hid  = (float*)d_ws + 1024 * 128;         // 64*256 f32 = 64 KB
    float* ws_loss = (float*)d_ws + 1024 * 128 + 64 * 256;  // 64 f32

    k1_pointfeat<<<1024, 256, 0, stream>>>(x, s, W1, b1, W2, ws_part);
    k2a_hidden<<<256, 256, 0, stream>>>(ws_part, b2, e, W3, b3, ws_hid);
    k2b_vq<<<64, 512, 0, stream>>>(ws_hid, W4, b4, cb, out, ws_loss);
    k3_loss<<<1, 64, 0, stream>>>(ws_loss, out);
}

// Round 13
// 47.600 us; speedup vs baseline: 1.2016x; 1.0369x over previous
//
#include <hip/hip_runtime.h>
#include <hip/hip_bf16.h>

typedef unsigned int u32;
typedef __attribute__((ext_vector_type(4))) unsigned int u32x4;
typedef __attribute__((ext_vector_type(8))) short s16x8;
typedef __attribute__((ext_vector_type(4))) float f32x4;

// bf16 RNE of a, returned as f32 bit pattern (low 16 cleared)
__device__ __forceinline__ u32 rne_hi(float a) {
    u32 u = __float_as_uint(a);
    return (u + 0x7FFFu + ((u >> 16) & 1u)) & 0xFFFF0000u;
}
// pack bf16(a0) (low16) | bf16(a1) (high16) via HW v_cvt_pk_bf16_f32
__device__ __forceinline__ u32 pk_bf16(float a0, float a1) {
    __hip_bfloat162 pk2 = __float22bfloat162_rn(make_float2(a0, a1));
    u32 r;
    __builtin_memcpy(&r, &pk2, 4);
    return r;
}

// Round-13 k1 = round-12 + two changes:
//  (1) LDS stride 36 -> 32 u32 with XOR-quad swizzle: u32 chunk c (16B) of row
//      r lives at r*32 + ((c ^ (r&7))*4). Every b128 read/write hits 8
//      distinct bank-quads per 8-lane phase by construction (kills the
//      2.1M measured conflicts); LDS 36.9 -> 32 KB.
//  (2) __launch_bounds__(256,4): pin unified VGPR+AGPR <= 128/wave so 4
//      blocks/CU actually fit (r12 without the bound ran at ~21% occupancy;
//      r6 with it ran at 31%). TLP is what overlaps the VALU/LDS/MFMA pipes.
__global__ __launch_bounds__(256, 4) void k1_pointfeat(
    const float* __restrict__ x, const float* __restrict__ s,
    const float* __restrict__ W1, const float* __restrict__ b1,
    const float* __restrict__ W2, float* __restrict__ ws_part)
{
    // [buf 2][plane 2][row 64][32 u32], swizzled chunks
    __shared__ __align__(16) u32 Hlds[2 * 2 * 64 * 32];
    const int tid   = threadIdx.x;
    const int lane  = tid & 63;
    const int point = tid & 63;
    const int kq    = __builtin_amdgcn_readfirstlane(tid >> 6); // wave = 32-feat tile
    const int rl    = lane & 15;
    const int kg2   = lane >> 4;

    const int p0 = blockIdx.x * 512;

    // W2 B-frags for feats kq*32 + n*16 + rl; k = kg2*8 + j + sl2*32 (32 regs)
    s16x8 wbh[2][2], wbl[2][2];
    #pragma unroll
    for (int n = 0; n < 2; ++n)
        #pragma unroll
        for (int sl2 = 0; sl2 < 2; ++sl2)
            #pragma unroll
            for (int j = 0; j < 8; ++j) {
                float f = W2[(size_t)(kg2 * 8 + j + sl2 * 32) * 128 + kq * 32 + n * 16 + rl];
                u32 hb = rne_hi(f);
                float lo = f - __uint_as_float(hb);
                u32 lb = rne_hi(lo);
                wbh[n][sl2][j] = (short)(hb >> 16);
                wbl[n][sl2][j] = (short)(lb >> 16);
            }

    float rmax0 = -3.402823466e38f, rmax1 = -3.402823466e38f;

    // swizzled write positions for this thread (row = point, chunks 2kq, 2kq+1)
    const int wr0 = point * 32 + ((2 * kq)     ^ (point & 7)) * 4;
    const int wr1 = point * 32 + ((2 * kq + 1) ^ (point & 7)) * 4;

    // compute layer1 (16 h values: this wave's kq k-quarter) + split + pack
#define STAGE_COMPUTE(PX, PY, PZ, PW, VH0, VH1, VL0, VL1)                      \
    {                                                                          \
        _Pragma("unroll")                                                      \
        for (int h = 0; h < 2; ++h) {                                          \
            u32 hp[4], lp[4];                                                  \
            _Pragma("unroll")                                                  \
            for (int c = 0; c < 4; ++c) {                                      \
                const int k0 = kq * 16 + h * 8 + c * 2;                        \
                float a0 = fmaf(PX, W1[k0],                                    \
                           fmaf(PY, W1[64 + k0],                               \
                           fmaf(PZ, W1[128 + k0],                              \
                           fmaf(PW, W1[192 + k0], b1[k0]))));                  \
                float a1 = fmaf(PX, W1[k0 + 1],                                \
                           fmaf(PY, W1[65 + k0],                               \
                           fmaf(PZ, W1[129 + k0],                              \
                           fmaf(PW, W1[193 + k0], b1[k0 + 1]))));              \
                a0 = a0 > 0.f ? a0 : 0.f;                                      \
                a1 = a1 > 0.f ? a1 : 0.f;                                      \
                u32 ph = pk_bf16(a0, a1);                                      \
                float h0 = __uint_as_float(ph << 16);                          \
                float h1 = __uint_as_float(ph & 0xFFFF0000u);                  \
                u32 pl = pk_bf16(a0 - h0, a1 - h1);                            \
                hp[c] = ph; lp[c] = pl;                                        \
            }                                                                  \
            if (h == 0) { VH0 = (u32x4){hp[0],hp[1],hp[2],hp[3]};              \
                          VL0 = (u32x4){lp[0],lp[1],lp[2],lp[3]}; }            \
            else        { VH1 = (u32x4){hp[0],hp[1],hp[2],hp[3]};              \
                          VL1 = (u32x4){lp[0],lp[1],lp[2],lp[3]}; }            \
        }                                                                      \
    }
    // buf base = GG&1 ? 4096 : 0; hi plane chunks at wr0/wr1, lo plane +2048
#define STAGE_WRITE(GG, VH0, VH1, VL0, VL1)                                    \
    {                                                                          \
        u32* Hw = &Hlds[((GG) & 1) * 4096];                                    \
        *(u32x4*)(Hw + wr0)        = VH0;                                      \
        *(u32x4*)(Hw + wr1)        = VH1;                                      \
        *(u32x4*)(Hw + 2048 + wr0) = VL0;                                      \
        *(u32x4*)(Hw + 2048 + wr1) = VL1;                                      \
    }

    // prologue: stage group 0 fully; prefetch coords for group 1
    {
        const int gp = p0 + point;
        float px = x[(size_t)gp * 3 + 0], py = x[(size_t)gp * 3 + 1];
        float pz = x[(size_t)gp * 3 + 2], pw = s[gp];
        u32x4 vh0, vh1, vl0, vl1;
        STAGE_COMPUTE(px, py, pz, pw, vh0, vh1, vl0, vl1)
        STAGE_WRITE(0, vh0, vh1, vl0, vl1)
    }
    float pxn, pyn, pzn, pwn;
    {
        const int gp = p0 + 64 + point;
        pxn = x[(size_t)gp * 3 + 0]; pyn = x[(size_t)gp * 3 + 1];
        pzn = x[(size_t)gp * 3 + 2]; pwn = s[gp];
    }

    // swizzled read offsets: row = m*16+rl, chunk = sl2*4+kg2
#define ARD(M, SL2) ((M) * 16 + rl) * 32 + ((((SL2) * 4 + kg2) ^ (rl & 7)) * 4)

    #pragma unroll 1
    for (int g = 0; g < 8; ++g) {
        __syncthreads();   // buf[g&1] staged by all waves
        const u32* Hb = &Hlds[(g & 1) * 4096];

        // issue sl2=0 A-frag reads (8 x b128)
        s16x8 ah0[4], al0[4];
        #pragma unroll
        for (int m = 0; m < 4; ++m) {
            ah0[m] = *(const s16x8*)(Hb + ARD(m, 0));
            al0[m] = *(const s16x8*)(Hb + 2048 + ARD(m, 0));
        }

        // stage-compute g+1 (VALU, independent of the ds_reads -> hides them)
        u32x4 vh0, vh1, vl0, vl1;
        if (g < 7) {
            STAGE_COMPUTE(pxn, pyn, pzn, pwn, vh0, vh1, vl0, vl1)
        }

        f32x4 acc[4][2] = {};   // [m][n], 8 independent chains
        // MFMA k-slab 0
        #pragma unroll
        for (int m = 0; m < 4; ++m)
            #pragma unroll
            for (int n = 0; n < 2; ++n)
                acc[m][n] = __builtin_amdgcn_mfma_f32_16x16x32_bf16(
                    ah0[m], wbh[n][0], acc[m][n], 0, 0, 0);
        #pragma unroll
        for (int m = 0; m < 4; ++m)
            #pragma unroll
            for (int n = 0; n < 2; ++n)
                acc[m][n] = __builtin_amdgcn_mfma_f32_16x16x32_bf16(
                    ah0[m], wbl[n][0], acc[m][n], 0, 0, 0);
        #pragma unroll
        for (int m = 0; m < 4; ++m)
            #pragma unroll
            for (int n = 0; n < 2; ++n)
                acc[m][n] = __builtin_amdgcn_mfma_f32_16x16x32_bf16(
                    al0[m], wbh[n][0], acc[m][n], 0, 0, 0);

        // issue sl2=1 A-frag reads + coords for g+2
        s16x8 ah1[4], al1[4];
        #pragma unroll
        for (int m = 0; m < 4; ++m) {
            ah1[m] = *(const s16x8*)(Hb + ARD(m, 1));
            al1[m] = *(const s16x8*)(Hb + 2048 + ARD(m, 1));
        }
        if (g < 6) {
            const int gp = p0 + (g + 2) * 64 + point;
            pxn = x[(size_t)gp * 3 + 0]; pyn = x[(size_t)gp * 3 + 1];
            pzn = x[(size_t)gp * 3 + 2]; pwn = s[gp];
        }

        // MFMA k-slab 1
        #pragma unroll
        for (int m = 0; m < 4; ++m)
            #pragma unroll
            for (int n = 0; n < 2; ++n)
                acc[m][n] = __builtin_amdgcn_mfma_f32_16x16x32_bf16(
                    ah1[m], wbh[n][1], acc[m][n], 0, 0, 0);
        #pragma unroll
        for (int m = 0; m < 4; ++m)
            #pragma unroll
            for (int n = 0; n < 2; ++n)
                acc[m][n] = __builtin_amdgcn_mfma_f32_16x16x32_bf16(
                    ah1[m], wbl[n][1], acc[m][n], 0, 0, 0);
        #pragma unroll
        for (int m = 0; m < 4; ++m)
            #pragma unroll
            for (int n = 0; n < 2; ++n)
                acc[m][n] = __builtin_amdgcn_mfma_f32_16x16x32_bf16(
                    al1[m], wbh[n][1], acc[m][n], 0, 0, 0);

        // stage-write g+1 (other buffer: no wave reads it until next barrier)
        if (g < 7) {
            STAGE_WRITE(g + 1, vh0, vh1, vl0, vl1)
        }

        // rmax last (acc drain)
        #pragma unroll
        for (int m = 0; m < 4; ++m)
            #pragma unroll
            for (int r = 0; r < 4; ++r) {
                rmax0 = fmaxf(rmax0, acc[m][0][r]);
                rmax1 = fmaxf(rmax1, acc[m][1][r]);
            }
    }
#undef ARD
#undef STAGE_COMPUTE
#undef STAGE_WRITE

    // lanes l, l^16, l^32, l^48 hold the same feature column
    rmax0 = fmaxf(rmax0, __shfl_xor(rmax0, 16, 64));
    rmax0 = fmaxf(rmax0, __shfl_xor(rmax0, 32, 64));
    rmax1 = fmaxf(rmax1, __shfl_xor(rmax1, 16, 64));
    rmax1 = fmaxf(rmax1, __shfl_xor(rmax1, 32, 64));
    if (lane < 16) {
        ws_part[blockIdx.x * 128 + kq * 32 + lane]      = rmax0;
        ws_part[blockIdx.x * 128 + kq * 32 + 16 + lane] = rmax1;
    }
}

// Hidden layer: block = (batch, 64-unit chunk); thread = (unit, i-quarter).
__global__ __launch_bounds__(256) void k2a_hidden(
    const float* __restrict__ ws_part, const float* __restrict__ b2,
    const float* __restrict__ e,
    const float* __restrict__ W3, const float* __restrict__ b3,
    float* __restrict__ ws_hid)
{
    const int blk = blockIdx.x;        // 256 = 64 batches x 4 chunks
    const int b   = blk >> 2;
    const int c   = blk & 3;
    const int tid = threadIdx.x;
    const int u   = tid & 63;
    const int part = tid >> 6;         // 0..3, i-range quarter
    __shared__ float comb[640];
    __shared__ float psum[4][64];

    for (int i = tid; i < 640; i += 256) {
        float v;
        if (i < 128) {
            const float* __restrict__ pp = ws_part + (size_t)b * 16 * 128 + i;
            float m = pp[0];
            #pragma unroll
            for (int t = 1; t < 16; ++t) m = fmaxf(m, pp[t * 128]);
            v = m + b2[i];
        } else {
            v = e[b * 512 + (i - 128)];
        }
        comb[i] = v;
    }
    __syncthreads();

    const int gu = c * 64 + u;
    const float* __restrict__ Wp = W3 + (size_t)(part * 160) * 256 + gu;
    const float* __restrict__ cp = comb + part * 160;
    float a = 0.f;
    for (int i = 0; i < 160; ++i) a = fmaf(cp[i], Wp[(size_t)i * 256], a);
    psum[part][u] = a;
    __syncthreads();
    if (tid < 64) {
        float hv = psum[0][u] + psum[1][u] + psum[2][u] + psum[3][u] + b3[gu];
        ws_hid[b * 256 + gu] = hv > 0.f ? hv : 0.f;
    }
}

// z_e + VQ + per-batch loss partial. 64 blocks x 512 threads.
__global__ __launch_bounds__(512) void k2b_vq(
    const float* __restrict__ ws_hid,
    const float* __restrict__ W4, const float* __restrict__ b4,
    const float* __restrict__ cb, float* __restrict__ out,
    float* __restrict__ ws_loss)
{
    const int b = blockIdx.x, tid = threadIdx.x;
    __shared__ float hid[256];
    __shared__ float psum[4][128];
    __shared__ float ze[128];
    __shared__ float red_d[512];
    __shared__ int   red_i[512];
    __shared__ float lred[128];
    __shared__ float zzs;

    if (tid < 256) hid[tid] = ws_hid[b * 256 + tid];
    __syncthreads();

    {
        const int u = tid & 127, part = tid >> 7;
        const float* __restrict__ Wp = W4 + (size_t)(part * 64) * 128 + u;
        const float* __restrict__ hp = hid + part * 64;
        float a = 0.f;
        for (int i = 0; i < 64; ++i) a = fmaf(hp[i], Wp[(size_t)i * 128], a);
        psum[part][u] = a;
    }
    __syncthreads();
    if (tid < 128) {
        float a = psum[0][tid] + psum[1][tid] + psum[2][tid] + psum[3][tid] + b4[tid];
        ze[tid] = a;
        out[8192 + b * 128 + tid] = a;     // z_e
    }
    __syncthreads();

    if (tid < 64) {
        float t = ze[tid] * ze[tid] + ze[tid + 64] * ze[tid + 64];
        #pragma unroll
        for (int d = 1; d < 64; d <<= 1) t += __shfl_xor(t, d, 64);
        if (tid == 0) zzs = t;
    }
    __syncthreads();

    {
        float dot = 0.f, cc = 0.f;
        const f32x4* __restrict__ cp = (const f32x4*)(cb + (size_t)tid * 128);
        for (int k4 = 0; k4 < 32; ++k4) {
            f32x4 v = cp[k4];
            dot = fmaf(ze[k4 * 4 + 0], v.x, dot);
            cc  = fmaf(v.x, v.x, cc);
            dot = fmaf(ze[k4 * 4 + 1], v.y, dot);
            cc  = fmaf(v.y, v.y, cc);
            dot = fmaf(ze[k4 * 4 + 2], v.z, dot);
            cc  = fmaf(v.z, v.z, cc);
            dot = fmaf(ze[k4 * 4 + 3], v.w, dot);
            cc  = fmaf(v.w, v.w, cc);
        }
        red_d[tid] = zzs - 2.f * dot + cc;
        red_i[tid] = tid;
    }
    __syncthreads();

    for (int sft = 256; sft >= 1; sft >>= 1) {
        if (tid < sft) {
            float da = red_d[tid], db = red_d[tid + sft];
            int   ia = red_i[tid], ib = red_i[tid + sft];
            if (db < da || (db == da && ib < ia)) { red_d[tid] = db; red_i[tid] = ib; }
        }
        __syncthreads();
    }
    const int bc = red_i[0];

    if (tid < 128) {
        float zq  = cb[(size_t)bc * 128 + tid];
        float zev = ze[tid];
        out[b * 128 + tid] = zev + (zq - zev);   // z_q_st
        float d = zq - zev;
        lred[tid] = d * d;
    }
    if (tid == 0) out[16386 + b] = (float)bc;
    __syncthreads();
    if (tid < 64) {
        float t = lred[tid] + lred[tid + 64];
        #pragma unroll
        for (int d = 1; d < 64; d <<= 1) t += __shfl_xor(t, d, 64);
        if (tid == 0) ws_loss[b] = t;
    }
}

// Single-wave loss finalize.
__global__ void k3_loss(const float* __restrict__ ws_loss, float* __restrict__ out)
{
    const int t = threadIdx.x;   // 64 threads
    float v = ws_loss[t];
    #pragma unroll
    for (int d = 1; d < 64; d <<= 1) v += __shfl_xor(v, d, 64);
    if (t == 0) {
        float m = v / 8192.f;
        out[16384] = m;   // codebook_loss
        out[16385] = m;   // commitment_loss (numerically identical)
    }
}

extern "C" void kernel_launch(void* const* d_in, const int* in_sizes, int n_in,
                              void* d_out, int out_size, void* d_ws, size_t ws_size,
                              hipStream_t stream) {
    const float* x  = (const float*)d_in[0];
    const float* s  = (const float*)d_in[1];
    const float* e  = (const float*)d_in[2];
    const float* W1 = (const float*)d_in[3];
    const float* b1 = (const float*)d_in[4];
    const float* W2 = (const float*)d_in[5];
    const float* b2 = (const float*)d_in[6];
    const float* W3 = (const float*)d_in[7];
    const float* b3 = (const float*)d_in[8];
    const float* W4 = (const float*)d_in[9];
    const float* b4 = (const float*)d_in[10];
    const float* cb = (const float*)d_in[11];
    float* out = (float*)d_out;

    float* ws_part = (float*)d_ws;                      // 1024*128 f32 = 512 KB
    float* ws_hid  = (float*)d_ws + 1024 * 128;         // 64*256 f32 = 64 KB
    float* ws_loss = (float*)d_ws + 1024 * 128 + 64 * 256;  // 64 f32

    k1_pointfeat<<<1024, 256, 0, stream>>>(x, s, W1, b1, W2, ws_part);
    k2a_hidden<<<256, 256, 0, stream>>>(ws_part, b2, e, W3, b3, ws_hid);
    k2b_vq<<<64, 512, 0, stream>>>(ws_hid, W4, b4, cb, out, ws_loss);
    k3_loss<<<1, 64, 0, stream>>>(ws_loss, out);
}